// Round 12
// baseline (1026.683 us; speedup 1.0000x reference)
//
#include <hip/hip_runtime.h>
#include <hip/hip_bf16.h>

#define HD 512      // d_model
#define NST 64      // d_state
#define NLAY 6
#define LSEQ 784
#define BB 64       // batch
#define CHK 7       // l-tiles (16 rows) per conv block; 49 = 7*7
#define NKA 848     // reversed+padded kernel array length (u16)
#define TOFF 800    // KA[t] = K[TOFF - t]; t in [17,800] real, else 0
#define LPADROWS 800  // Vb row capacity (16 rows slack for j over-read)
#define UTS 20      // UT row stride (dwords): 16B-aligned rows, <=2-way banks
#define KSTR 850    // u16 stride between shifted K copies

typedef unsigned short u16;
typedef short s8v __attribute__((ext_vector_type(8)));   // 8 bf16 (4 VGPR)
typedef float f4v __attribute__((ext_vector_type(4)));   // MFMA acc
typedef u16  u4h __attribute__((ext_vector_type(4)));    // ushort4 (8B)

// fp32 -> bf16 bits, round-to-nearest-even
__device__ __forceinline__ unsigned f2b(float f)
{
    unsigned u = __builtin_bit_cast(unsigned, f);
    return (u + 0x7FFFu + ((u >> 16) & 1u)) >> 16;
}
__device__ __forceinline__ float b2f16(u16 v)
{
    unsigned u = ((unsigned)v) << 16;
    return __builtin_bit_cast(float, u);
}

// ---------------------------------------------------------------------------
// Per (layer,h,n): lambda = exp(dt*A), dtA, 2*Cd. Layout [i][h][n].
// ---------------------------------------------------------------------------
__global__ void precompute_k(const float* __restrict__ log_dt,
                             const float* __restrict__ log_A_real,
                             const float* __restrict__ A_imag,
                             const float* __restrict__ C_re,
                             const float* __restrict__ C_im,
                             float* __restrict__ lamr, float* __restrict__ lami,
                             float* __restrict__ dtr,  float* __restrict__ dti,
                             float* __restrict__ c2r,  float* __restrict__ c2i)
{
    int t = blockIdx.x * 256 + threadIdx.x;
    if (t >= NLAY * HD * NST) return;
    int ih = t >> 6;                       // i*HD + h
    float dt  = expf(log_dt[ih]);
    float are = -expf(log_A_real[t]);
    float aim = A_imag[t];
    float dr = are * dt, di = aim * dt;
    float er = expf(dr);
    float sn, cs; __sincosf(di, &sn, &cs);
    float lr = er * cs, li = er * sn;      // lambda
    float e1r = lr - 1.0f, e1i = li;
    float den = are * are + aim * aim;
    float qr = (e1r * are + e1i * aim) / den;
    float qi = (e1i * are - e1r * aim) / den;
    float crv = C_re[t], civ = C_im[t];
    lamr[t] = lr; lami[t] = li; dtr[t] = dr; dti[t] = di;
    c2r[t] = 2.0f * (crv * qr - civ * qi);
    c2i[t] = 2.0f * (crv * qi + civ * qr);
}

// ---------------------------------------------------------------------------
// Build KA[i][h][t] (bf16): reversed, zero-padded conv kernel.
// KA[TOFF - d] = K[d], d = 0..783; all other slots zero.
// ---------------------------------------------------------------------------
__global__ void kq_k(const float* __restrict__ lamr, const float* __restrict__ lami,
                     const float* __restrict__ dtr,  const float* __restrict__ dti,
                     const float* __restrict__ c2r,  const float* __restrict__ c2i,
                     u16* __restrict__ KA)
{
    int t = blockIdx.x * 256 + threadIdx.x;   // < 6*512*49
    int dc = t % 49;
    int ih = t / 49;                          // i*HD + h
    int d0 = dc * 16;
    float acc[16];
#pragma unroll
    for (int k = 0; k < 16; k++) acc[k] = 0.f;
    int base = ih * 64;
    for (int n = 0; n < 64; n++) {
        float lr = lamr[base + n], li = lami[base + n];
        float dr = dtr[base + n],  di = dti[base + n];
        float cr = c2r[base + n],  ci = c2i[base + n];
        float e = __expf(dr * (float)d0);
        float sn, cs; __sincosf(di * (float)d0, &sn, &cs);
        float pr = e * cs, pi = e * sn;       // lam^d0
#pragma unroll
        for (int k = 0; k < 16; k++) {
            acc[k] = fmaf(cr, pr, fmaf(-ci, pi, acc[k]));
            float nr = pr * lr - pi * li;
            pi = fmaf(pr, li, pi * lr);
            pr = nr;
        }
    }
    u16* kap = KA + (size_t)ih * NKA;
#pragma unroll
    for (int k = 0; k < 16; k++)
        kap[TOFF - (d0 + k)] = (u16)f2b(acc[k]);
    if (dc == 0)  for (int z = TOFF + 1; z < NKA; z++) kap[z] = 0;
    if (dc == 48) for (int z = 0; z < TOFF - 783; z++) kap[z] = 0;
}

// ---------------------------------------------------------------------------
// Encoder into bf16 [l][h][b]: Vb = bf16(x[b,l]*ew[h]+eb[h])
// ---------------------------------------------------------------------------
__global__ void encoder_k(const float* __restrict__ x, const float* __restrict__ ew,
                          const float* __restrict__ eb, u16* __restrict__ Vb)
{
    size_t g = (size_t)blockIdx.x * 256 + threadIdx.x;
    int b = (int)(g & 63);
    int h = (int)((g >> 6) & 511);
    int l = (int)(g >> 15);
    Vb[g] = (u16)f2b(fmaf(x[b * LSEQ + l], ew[h], eb[h]));
}

// ---------------------------------------------------------------------------
// MFMA causal-Toeplitz conv + residual: V2 = bf16(conv(K_h,Vb) + (1+D_h)*Vb).
// Block = (h, chunk c of 7 l-tiles) x 4 waves (4 b-tiles of 16).
// TOEPLITZ SHIFT REUSE: A-frag(lt, jt+1) == A-frag(lt-2, jt), so the 7
// A-frags live in registers, rotate by 2 each jt; only 2 fresh frags are
// loaded per jt (guarded: skip when that l-tile is already finished).
// K copies stored with per-copy shift (8-s)&7 and TOFF=800 => every lane's
// A-frag address is 16B-aligned -> single ds_read_b128 per frag.
// B staged by thread=(b, j-group): 8 coalesced u16 loads -> 1 ds_write_b128;
// B-frag = 1 ds_read_b128 (UTS=20 rows 16B-aligned, <=2-way banks).
// One barrier per 32-j step; next tile's global loads issued before compute.
// ---------------------------------------------------------------------------
__global__ __launch_bounds__(256)
void conv_k(const u16* __restrict__ Vb, u16* __restrict__ V2,
            const u16* __restrict__ KA, const float* __restrict__ Dvec)
{
    __shared__ __align__(16) u16 KR[6816];           // 8 shifted copies
    __shared__ __align__(16) unsigned UT[2][64 * UTS];

    const int thr = threadIdx.x;
    const int h   = blockIdx.x & 511;
    const int c   = blockIdx.x >> 9;         // 0..6
    const int wid = thr >> 6;                // b-tile
    const int lane = thr & 63;
    const int n = lane & 15;
    const int q = lane >> 4;
    const int JTN = (112 * c + 111) / 32 + 1;

    // stage 8 shifted copies: KR[KSTR*s + ((8-s)&7) + i] = kap[i]
    const u16* kap = KA + (size_t)h * NKA;
    {
        int s = thr & 7, ch = thr >> 3;      // 32 chunks x 27 (covers 848)
        int i0 = ch * 27;
        int i1 = (i0 + 27 < NKA) ? (i0 + 27) : NKA;
        u16* kr = KR + KSTR * s + ((8 - s) & 7);
        for (int i = i0; i < i1; i++) kr[i] = kap[i];
    }

    // B staging mapping: thread = (sb = batch 0..63, sg = j-group 0..3)
    const int sb = thr & 63;
    const int sg = thr >> 6;
    {   // stage tile jt=0: rows j = 8*sg + r
        const u16* vp = &Vb[((size_t)(8 * sg) * HD + h) * BB + sb];
        u16 rv[8];
#pragma unroll
        for (int r = 0; r < 8; r++) rv[r] = vp[(size_t)r * HD * BB];
        uint4 pk;
        pk.x = rv[0] | ((unsigned)rv[1] << 16);
        pk.y = rv[2] | ((unsigned)rv[3] << 16);
        pk.z = rv[4] | ((unsigned)rv[5] << 16);
        pk.w = rv[6] | ((unsigned)rv[7] << 16);
        *(uint4*)__builtin_assume_aligned(&UT[0][sb * UTS + 4 * sg], 16) = pk;
    }
    __syncthreads();

    f4v acc[CHK];
#pragma unroll
    for (int i = 0; i < CHK; i++) acc[i] = (f4v){0.f, 0.f, 0.f, 0.f};

    const float dcoef = 1.0f + Dvec[h];

    // per-lane A base: copy s=n&7, addr(lt,jt) = krb + 32*jt + 16*(6-lt)
    const int s = n & 7;
    const u16* krb = KR + KSTR * s + ((8 - s) & 7)
                     + (TOFF - 112 * c - 96) + 8 * q - n;
    // B-frag base pointers (per buffer)
    const unsigned* bb0 = &UT[0][(wid * 16 + n) * UTS + 4 * q];
    const unsigned* bb1 = &UT[1][(wid * 16 + n) * UTS + 4 * q];

    // prologue: load all 7 A-frags for jt=0 (all active at j0=0)
    s8v af[CHK];
#pragma unroll
    for (int lt = 0; lt < CHK; lt++)
        af[lt] = *(const s8v*)__builtin_assume_aligned(krb + 16 * (6 - lt), 16);

    for (int jt = 0; jt < JTN; ++jt) {
        const int j0 = jt * 32;
        // issue next tile's global loads (consumed after compute)
        u16 rv[8];
        const bool more = (jt + 1) < JTN;
        if (more) {
            const u16* vp = &Vb[((size_t)(32 * (jt + 1) + 8 * sg) * HD + h) * BB + sb];
#pragma unroll
            for (int r = 0; r < 8; r++) rv[r] = vp[(size_t)r * HD * BB];
        }
        // B fragment (same for all l-tiles this step)
        const unsigned* bb = (jt & 1) ? bb1 : bb0;
        union { unsigned u[4]; s8v v; } bu;
        *(uint4*)bu.u = *(const uint4*)__builtin_assume_aligned(bb, 16);

        // fresh A-frags for jt+1 (positions 0,1), guarded by tile activity
        s8v nf0, nf1;
        const bool a0 = 32 * (jt + 1) <= 112 * c + 15;
        const bool a1 = 32 * (jt + 1) <= 112 * c + 31;
        const u16* apn = krb + 32 * (jt + 1);
        if (a1) nf1 = *(const s8v*)__builtin_assume_aligned(apn + 80, 16);
        if (a0) nf0 = *(const s8v*)__builtin_assume_aligned(apn + 96, 16);

#pragma unroll
        for (int lt = 0; lt < CHK; ++lt) {
            if (16 * (c * CHK + lt) + 15 < j0) continue;   // tile done (uniform)
            union { s8v v; } au; au.v = af[lt];
            acc[lt] = __builtin_amdgcn_mfma_f32_16x16x32_bf16(au.v, bu.v, acc[lt], 0, 0, 0);
        }
        // rotate: af(lt, jt+1) = af(lt-2, jt)
#pragma unroll
        for (int lt = CHK - 1; lt >= 2; --lt) af[lt] = af[lt - 2];
        if (a1) af[1] = nf1;
        if (a0) af[0] = nf0;

        if (more) {
            uint4 pk;
            pk.x = rv[0] | ((unsigned)rv[1] << 16);
            pk.y = rv[2] | ((unsigned)rv[3] << 16);
            pk.z = rv[4] | ((unsigned)rv[5] << 16);
            pk.w = rv[6] | ((unsigned)rv[7] << 16);
            *(uint4*)__builtin_assume_aligned(&UT[(jt & 1) ^ 1][sb * UTS + 4 * sg], 16) = pk;
        }
        __syncthreads();
    }

    // epilogue: V2 = bf16(y + (1+D)*u)  (pre-LN residual)
#pragma unroll
    for (int lt = 0; lt < CHK; ++lt) {
        const int l0 = (c * CHK + lt) * 16;
#pragma unroll
        for (int r = 0; r < 4; ++r) {
            int l = l0 + q * 4 + r;
            size_t a = ((size_t)l * HD + h) * BB + wid * 16 + n;
            V2[a] = (u16)f2b(fmaf(dcoef, b2f16(Vb[a]), acc[lt][r]));
        }
    }
}

// ---------------------------------------------------------------------------
// LayerNorm over h in [l][h][b]; bf16 in/out, fp32 math, u4h-vectorized.
// Block = one l, 512 thr: thread (qd = b-quad, hg = h-group of 16).
// ---------------------------------------------------------------------------
__global__ __launch_bounds__(512)
void lnT_k(const u16* __restrict__ src, u16* __restrict__ dst,
           const float* __restrict__ gp, const float* __restrict__ bp)
{
    __shared__ float redS[32][68], redQ[32][68];
    __shared__ float mus[64], rss[64];
    __shared__ float gs[512], bs[512];
    const int thr = threadIdx.x;
    const int qd = thr & 15;          // b-quad (b = 4*qd + i)
    const int hg = thr >> 4;          // 0..31 (h = hg*16 + k)
    const size_t l = blockIdx.x;
    gs[thr] = gp[thr]; bs[thr] = bp[thr];

    const u16* sp = &src[(l * HD + hg * 16) * BB + 4 * qd];
    float v[64];
    float s0 = 0, s1 = 0, s2 = 0, s3 = 0, q0 = 0, q1 = 0, q2 = 0, q3 = 0;
#pragma unroll
    for (int k = 0; k < 16; k++) {
        u4h r = *(const u4h*)(sp + (size_t)k * BB);
        float x0 = b2f16(r[0]), x1 = b2f16(r[1]);
        float x2 = b2f16(r[2]), x3 = b2f16(r[3]);
        v[4 * k + 0] = x0; v[4 * k + 1] = x1; v[4 * k + 2] = x2; v[4 * k + 3] = x3;
        s0 += x0; s1 += x1; s2 += x2; s3 += x3;
        q0 = fmaf(x0, x0, q0); q1 = fmaf(x1, x1, q1);
        q2 = fmaf(x2, x2, q2); q3 = fmaf(x3, x3, q3);
    }
    redS[hg][4 * qd + 0] = s0; redS[hg][4 * qd + 1] = s1;
    redS[hg][4 * qd + 2] = s2; redS[hg][4 * qd + 3] = s3;
    redQ[hg][4 * qd + 0] = q0; redQ[hg][4 * qd + 1] = q1;
    redQ[hg][4 * qd + 2] = q2; redQ[hg][4 * qd + 3] = q3;
    __syncthreads();
    if (thr < 64) {
        float ts = 0.f, tq = 0.f;
#pragma unroll
        for (int g = 0; g < 32; g++) { ts += redS[g][thr]; tq += redQ[g][thr]; }
        float mu = ts * (1.0f / HD);
        mus[thr] = mu;
        rss[thr] = rsqrtf(tq * (1.0f / HD) - mu * mu + 1e-5f);
    }
    __syncthreads();
    float mu0 = mus[4 * qd], mu1 = mus[4 * qd + 1], mu2 = mus[4 * qd + 2], mu3 = mus[4 * qd + 3];
    float rs0 = rss[4 * qd], rs1 = rss[4 * qd + 1], rs2 = rss[4 * qd + 2], rs3 = rss[4 * qd + 3];
    u16* dp = &dst[(l * HD + hg * 16) * BB + 4 * qd];
#pragma unroll
    for (int k = 0; k < 16; k++) {
        float g = gs[hg * 16 + k], b = bs[hg * 16 + k];
        u4h w;
        w[0] = (u16)f2b(fmaf((v[4 * k + 0] - mu0) * rs0, g, b));
        w[1] = (u16)f2b(fmaf((v[4 * k + 1] - mu1) * rs1, g, b));
        w[2] = (u16)f2b(fmaf((v[4 * k + 2] - mu2) * rs2, g, b));
        w[3] = (u16)f2b(fmaf((v[4 * k + 3] - mu3) * rs3, g, b));
        *(u4h*)(dp + (size_t)k * BB) = w;
    }
}

// ---------------------------------------------------------------------------
// Mean-pool over l from bf16 Vb: PO[h*64+b] = mean_l Vb[l][h][b].
// ---------------------------------------------------------------------------
__global__ void pool_k(const u16* __restrict__ Vb, float* __restrict__ PO)
{
    __shared__ float red[4][64];
    int h = blockIdx.x;
    int b = threadIdx.x & 63;
    int lg = threadIdx.x >> 6;               // 0..3
    const u16* p = &Vb[(size_t)h * BB + b];
    float s = 0.f;
    for (int l = lg; l < LSEQ; l += 4) s += b2f16(p[(size_t)l * HD * BB]);
    red[lg][b] = s;
    __syncthreads();
    if (threadIdx.x < 64) {
        float t = red[0][b] + red[1][b] + red[2][b] + red[3][b];
        PO[h * BB + b] = t * (1.0f / LSEQ);
    }
}

// ---------------------------------------------------------------------------
// Decoder: out[b,c] = PO[:,b] . dec_w[:,c] + dec_b[c]
// ---------------------------------------------------------------------------
__global__ void dec_k(const float* __restrict__ PO, const float* __restrict__ w,
                      const float* __restrict__ bias, float* __restrict__ out)
{
    int t = blockIdx.x * 256 + threadIdx.x;
    if (t >= BB * 10) return;
    int cc = t % 10, b = t / 10;
    float acc = bias[cc];
    for (int hh = 0; hh < HD; hh++)
        acc = fmaf(PO[hh * BB + b], w[hh * 10 + cc], acc);
    out[t] = acc;
}

// ---------------------------------------------------------------------------
extern "C" void kernel_launch(void* const* d_in, const int* in_sizes, int n_in,
                              void* d_out, int out_size, void* d_ws, size_t ws_size,
                              hipStream_t stream)
{
    const float* x   = (const float*)d_in[0];
    const float* ew  = (const float*)d_in[1];
    const float* eb  = (const float*)d_in[2];
    const float* ldt = (const float*)d_in[3];
    const float* lar = (const float*)d_in[4];
    const float* aim = (const float*)d_in[5];
    const float* cre = (const float*)d_in[6];
    const float* cim = (const float*)d_in[7];
    const float* Dp  = (const float*)d_in[8];
    const float* lng = (const float*)d_in[9];
    const float* lnb = (const float*)d_in[10];
    const float* fng = (const float*)d_in[11];
    const float* fnb = (const float*)d_in[12];
    const float* dw  = (const float*)d_in[13];
    const float* db  = (const float*)d_in[14];
    float* out = (float*)d_out;

    const size_t SZ  = (size_t)BB * LSEQ * HD;       // 25,690,112 elems
    const size_t SZB = (size_t)BB * LPADROWS * HD;   // 26,214,400 u16 slots
    const size_t PP  = (size_t)NLAY * HD * NST;      // 196,608
    u16*   Vb  = (u16*)d_ws;                // bf16 residual stream [l][h][b]
    u16*   V2  = Vb + SZB;                  // bf16 pre-LN buffer
    float* PAR = (float*)(V2 + SZ);
    float* lamr = PAR,        * lami = PAR + PP;
    float* dtr  = PAR + 2*PP, * dti  = PAR + 3*PP;
    float* c2r  = PAR + 4*PP, * c2i  = PAR + 5*PP;
    u16* KA = (u16*)(PAR + 6 * PP);                  // 6*512*848 u16
    float* PO = PAR + 6 * PP + (NLAY * HD * NKA) / 2;
    // total ~116 MB

    precompute_k<<<(NLAY * HD * NST + 255) / 256, 256, 0, stream>>>(
        ldt, lar, aim, cre, cim, lamr, lami, dtr, dti, c2r, c2i);
    kq_k<<<(NLAY * HD * 49) / 256, 256, 0, stream>>>(
        lamr, lami, dtr, dti, c2r, c2i, KA);
    encoder_k<<<(int)(SZ / 256), 256, 0, stream>>>(x, ew, eb, Vb);

    for (int i = 0; i < NLAY; i++) {
        conv_k<<<512 * CHK, 256, 0, stream>>>(
            Vb, V2, KA + (size_t)i * HD * NKA, Dp + i * HD);
        lnT_k<<<LSEQ, 512, 0, stream>>>(V2, Vb, lng + i * HD, lnb + i * HD);
    }
    lnT_k<<<LSEQ, 512, 0, stream>>>(Vb, Vb, fng, fnb);  // final LN in place
    pool_k<<<HD, 256, 0, stream>>>(Vb, PO);
    dec_k<<<(BB * 10 + 255) / 256, 256, 0, stream>>>(PO, dw, db, out);
}

// Round 13
// 718.399 us; speedup vs baseline: 1.4291x; 1.4291x over previous
//
#include <hip/hip_runtime.h>
#include <hip/hip_bf16.h>

#define HD 512      // d_model
#define NST 64      // d_state
#define NLAY 6
#define LSEQ 784
#define BB 64       // batch
#define CHK 7       // l-tiles (16 rows) per conv block; 49 = 7*7
#define NKA 848     // reversed+padded kernel array length (u16)
#define TOFF 800    // KA[t] = K[TOFF - t]; t in [17,800] real, else 0
#define LPADROWS 800  // Vb row capacity (16 rows slack for j over-read)
#define UTS 19      // UT row stride (dwords): <=2-way banks on stage+read
#define KSTR 850    // u16 stride between shifted K copies

typedef unsigned short u16;
typedef short s8v __attribute__((ext_vector_type(8)));   // 8 bf16 (4 VGPR)
typedef float f4v __attribute__((ext_vector_type(4)));   // MFMA acc
typedef u16  u4h __attribute__((ext_vector_type(4)));    // ushort4 (8B)

// fp32 -> bf16 bits, round-to-nearest-even
__device__ __forceinline__ unsigned f2b(float f)
{
    unsigned u = __builtin_bit_cast(unsigned, f);
    return (u + 0x7FFFu + ((u >> 16) & 1u)) >> 16;
}
__device__ __forceinline__ float b2f16(u16 v)
{
    unsigned u = ((unsigned)v) << 16;
    return __builtin_bit_cast(float, u);
}

// ---------------------------------------------------------------------------
// Per (layer,h,n): lambda = exp(dt*A), dtA, 2*Cd. Layout [i][h][n].
// ---------------------------------------------------------------------------
__global__ void precompute_k(const float* __restrict__ log_dt,
                             const float* __restrict__ log_A_real,
                             const float* __restrict__ A_imag,
                             const float* __restrict__ C_re,
                             const float* __restrict__ C_im,
                             float* __restrict__ lamr, float* __restrict__ lami,
                             float* __restrict__ dtr,  float* __restrict__ dti,
                             float* __restrict__ c2r,  float* __restrict__ c2i)
{
    int t = blockIdx.x * 256 + threadIdx.x;
    if (t >= NLAY * HD * NST) return;
    int ih = t >> 6;                       // i*HD + h
    float dt  = expf(log_dt[ih]);
    float are = -expf(log_A_real[t]);
    float aim = A_imag[t];
    float dr = are * dt, di = aim * dt;
    float er = expf(dr);
    float sn, cs; __sincosf(di, &sn, &cs);
    float lr = er * cs, li = er * sn;      // lambda
    float e1r = lr - 1.0f, e1i = li;
    float den = are * are + aim * aim;
    float qr = (e1r * are + e1i * aim) / den;
    float qi = (e1i * are - e1r * aim) / den;
    float crv = C_re[t], civ = C_im[t];
    lamr[t] = lr; lami[t] = li; dtr[t] = dr; dti[t] = di;
    c2r[t] = 2.0f * (crv * qr - civ * qi);
    c2i[t] = 2.0f * (crv * qi + civ * qr);
}

// ---------------------------------------------------------------------------
// Build KA[i][h][t] (bf16): reversed, zero-padded conv kernel.
// KA[TOFF - d] = K[d], d = 0..783; all other slots zero.
// ---------------------------------------------------------------------------
__global__ void kq_k(const float* __restrict__ lamr, const float* __restrict__ lami,
                     const float* __restrict__ dtr,  const float* __restrict__ dti,
                     const float* __restrict__ c2r,  const float* __restrict__ c2i,
                     u16* __restrict__ KA)
{
    int t = blockIdx.x * 256 + threadIdx.x;   // < 6*512*49
    int dc = t % 49;
    int ih = t / 49;                          // i*HD + h
    int d0 = dc * 16;
    float acc[16];
#pragma unroll
    for (int k = 0; k < 16; k++) acc[k] = 0.f;
    int base = ih * 64;
    for (int n = 0; n < 64; n++) {
        float lr = lamr[base + n], li = lami[base + n];
        float dr = dtr[base + n],  di = dti[base + n];
        float cr = c2r[base + n],  ci = c2i[base + n];
        float e = __expf(dr * (float)d0);
        float sn, cs; __sincosf(di * (float)d0, &sn, &cs);
        float pr = e * cs, pi = e * sn;       // lam^d0
#pragma unroll
        for (int k = 0; k < 16; k++) {
            acc[k] = fmaf(cr, pr, fmaf(-ci, pi, acc[k]));
            float nr = pr * lr - pi * li;
            pi = fmaf(pr, li, pi * lr);
            pr = nr;
        }
    }
    u16* kap = KA + (size_t)ih * NKA;
#pragma unroll
    for (int k = 0; k < 16; k++)
        kap[TOFF - (d0 + k)] = (u16)f2b(acc[k]);
    if (dc == 0)  for (int z = TOFF + 1; z < NKA; z++) kap[z] = 0;
    if (dc == 48) for (int z = 0; z < TOFF - 783; z++) kap[z] = 0;
}

// ---------------------------------------------------------------------------
// Encoder into bf16 [l][h][b]: Vb = bf16(x[b,l]*ew[h]+eb[h])
// ---------------------------------------------------------------------------
__global__ void encoder_k(const float* __restrict__ x, const float* __restrict__ ew,
                          const float* __restrict__ eb, u16* __restrict__ Vb)
{
    size_t g = (size_t)blockIdx.x * 256 + threadIdx.x;
    int b = (int)(g & 63);
    int h = (int)((g >> 6) & 511);
    int l = (int)(g >> 15);
    Vb[g] = (u16)f2b(fmaf(x[b * LSEQ + l], ew[h], eb[h]));
}

// ---------------------------------------------------------------------------
// MFMA causal-Toeplitz conv + residual: V2 = bf16(conv(K_h,Vb) + (1+D_h)*Vb).
// Block = (h, chunk c of 7 l-tiles) x 4 waves (4 b-tiles of 16).
// A-frags: 8 lane-shifted K copies KR[KSTR*s + ((8-s)&7) + i] = K_rev[i],
// s = n&7 -> every lane's A-frag address is 16B-aligned -> ONE ds_read_b128
// per frag (round-12 verified layout; conflicts measured ~1.7e6).
// B staged as in round 11: thread=(jj,bq) loads 2 coalesced u4h rows, packs
// 4 dwords, writes 4 b32 (stride 19 => <=2-way); B-frag = 4 b32 reads.
// One barrier per 32-j step; next tile's global loads issued before compute.
// NO register A-queue (round-12 lesson: runtime-trip rotation costs VALU
// movs + VGPR pressure and loses more than the LDS reads it saves).
// ---------------------------------------------------------------------------
__global__ __launch_bounds__(256)
void conv_k(const u16* __restrict__ Vb, u16* __restrict__ V2,
            const u16* __restrict__ KA, const float* __restrict__ Dvec)
{
    __shared__ __align__(16) u16 KR[6816];           // 8 shifted copies
    __shared__ __align__(16) unsigned UT[2][64 * UTS];

    const int thr = threadIdx.x;
    const int h   = blockIdx.x & 511;
    const int c   = blockIdx.x >> 9;         // 0..6
    const int wid = thr >> 6;                // b-tile
    const int lane = thr & 63;
    const int n = lane & 15;
    const int q = lane >> 4;
    const int JTN = (112 * c + 111) / 32 + 1;

    // stage 8 shifted copies: KR[KSTR*s + ((8-s)&7) + i] = kap[i]
    const u16* kap = KA + (size_t)h * NKA;
    {
        int s = thr & 7, ch = thr >> 3;      // 32 chunks x 27 (covers 848)
        int i0 = ch * 27;
        int i1 = (i0 + 27 < NKA) ? (i0 + 27) : NKA;
        u16* kr = KR + KSTR * s + ((8 - s) & 7);
        for (int i = i0; i < i1; i++) kr[i] = kap[i];
    }

    // B staging mapping: thread = (jj = j-pair 0..15, bq = b-quad 0..15)
    const int jj = thr >> 4;
    const int bq = thr & 15;
    {   // stage tile jt=0
        const u16* p = &Vb[((size_t)(2 * jj) * HD + h) * BB + 4 * bq];
        u4h r0 = *(const u4h*)p;
        u4h r1 = *(const u4h*)(p + (size_t)HD * BB);
        unsigned* up = &UT[0][0];
#pragma unroll
        for (int i = 0; i < 4; i++)
            up[(4 * bq + i) * UTS + jj] = (unsigned)r0[i] | ((unsigned)r1[i] << 16);
    }
    __syncthreads();

    f4v acc[CHK];
#pragma unroll
    for (int i = 0; i < CHK; i++) acc[i] = (f4v){0.f, 0.f, 0.f, 0.f};

    const float dcoef = 1.0f + Dvec[h];

    // per-lane A base: copy s=n&7, addr(lt,jt) = krb + 32*jt + 16*(6-lt)
    const int s = n & 7;
    const u16* krb = KR + KSTR * s + ((8 - s) & 7)
                     + (TOFF - 112 * c - 96) + 8 * q - n;
    // B-frag base pointers (per buffer)
    const unsigned* bb0 = &UT[0][(wid * 16 + n) * UTS + 4 * q];
    const unsigned* bb1 = &UT[1][(wid * 16 + n) * UTS + 4 * q];

    for (int jt = 0; jt < JTN; ++jt) {
        const int j0 = jt * 32;
        // issue next tile's global loads (consumed after compute)
        u4h r0, r1;
        const bool more = (jt + 1) < JTN;
        if (more) {
            int j = (jt + 1) * 32 + 2 * jj;  // rows >783: slack rows, zero-A kills
            const u16* p = &Vb[((size_t)j * HD + h) * BB + 4 * bq];
            r0 = *(const u4h*)p;
            r1 = *(const u4h*)(p + (size_t)HD * BB);
        }
        // B fragment (same for all l-tiles this step)
        const unsigned* bb = (jt & 1) ? bb1 : bb0;
        union { unsigned u[4]; s8v v; } bu;
        bu.u[0] = bb[0]; bu.u[1] = bb[1]; bu.u[2] = bb[2]; bu.u[3] = bb[3];

        const u16* ap0 = krb + j0;
#pragma unroll
        for (int lt = 0; lt < CHK; ++lt) {
            if (16 * (c * CHK + lt) + 15 < j0) continue;   // tile done (uniform)
            union { s8v v; } au;
            au.v = *(const s8v*)__builtin_assume_aligned(ap0 + 16 * (6 - lt), 16);
            acc[lt] = __builtin_amdgcn_mfma_f32_16x16x32_bf16(au.v, bu.v, acc[lt], 0, 0, 0);
        }
        if (more) {
            unsigned* up = &UT[(jt & 1) ^ 1][0];
#pragma unroll
            for (int i = 0; i < 4; i++)
                up[(4 * bq + i) * UTS + jj] = (unsigned)r0[i] | ((unsigned)r1[i] << 16);
        }
        __syncthreads();
    }

    // epilogue: V2 = bf16(y + (1+D)*u)  (pre-LN residual)
#pragma unroll
    for (int lt = 0; lt < CHK; ++lt) {
        const int l0 = (c * CHK + lt) * 16;
#pragma unroll
        for (int r = 0; r < 4; ++r) {
            int l = l0 + q * 4 + r;
            size_t a = ((size_t)l * HD + h) * BB + wid * 16 + n;
            V2[a] = (u16)f2b(fmaf(dcoef, b2f16(Vb[a]), acc[lt][r]));
        }
    }
}

// ---------------------------------------------------------------------------
// LayerNorm over h in [l][h][b]; bf16 in/out, fp32 math, u4h-vectorized.
// Block = one l, 512 thr: thread (qd = b-quad, hg = h-group of 16).
// ---------------------------------------------------------------------------
__global__ __launch_bounds__(512)
void lnT_k(const u16* __restrict__ src, u16* __restrict__ dst,
           const float* __restrict__ gp, const float* __restrict__ bp)
{
    __shared__ float redS[32][68], redQ[32][68];
    __shared__ float mus[64], rss[64];
    __shared__ float gs[512], bs[512];
    const int thr = threadIdx.x;
    const int qd = thr & 15;          // b-quad (b = 4*qd + i)
    const int hg = thr >> 4;          // 0..31 (h = hg*16 + k)
    const size_t l = blockIdx.x;
    gs[thr] = gp[thr]; bs[thr] = bp[thr];

    const u16* sp = &src[(l * HD + hg * 16) * BB + 4 * qd];
    float v[64];
    float s0 = 0, s1 = 0, s2 = 0, s3 = 0, q0 = 0, q1 = 0, q2 = 0, q3 = 0;
#pragma unroll
    for (int k = 0; k < 16; k++) {
        u4h r = *(const u4h*)(sp + (size_t)k * BB);
        float x0 = b2f16(r[0]), x1 = b2f16(r[1]);
        float x2 = b2f16(r[2]), x3 = b2f16(r[3]);
        v[4 * k + 0] = x0; v[4 * k + 1] = x1; v[4 * k + 2] = x2; v[4 * k + 3] = x3;
        s0 += x0; s1 += x1; s2 += x2; s3 += x3;
        q0 = fmaf(x0, x0, q0); q1 = fmaf(x1, x1, q1);
        q2 = fmaf(x2, x2, q2); q3 = fmaf(x3, x3, q3);
    }
    redS[hg][4 * qd + 0] = s0; redS[hg][4 * qd + 1] = s1;
    redS[hg][4 * qd + 2] = s2; redS[hg][4 * qd + 3] = s3;
    redQ[hg][4 * qd + 0] = q0; redQ[hg][4 * qd + 1] = q1;
    redQ[hg][4 * qd + 2] = q2; redQ[hg][4 * qd + 3] = q3;
    __syncthreads();
    if (thr < 64) {
        float ts = 0.f, tq = 0.f;
#pragma unroll
        for (int g = 0; g < 32; g++) { ts += redS[g][thr]; tq += redQ[g][thr]; }
        float mu = ts * (1.0f / HD);
        mus[thr] = mu;
        rss[thr] = rsqrtf(tq * (1.0f / HD) - mu * mu + 1e-5f);
    }
    __syncthreads();
    float mu0 = mus[4 * qd], mu1 = mus[4 * qd + 1], mu2 = mus[4 * qd + 2], mu3 = mus[4 * qd + 3];
    float rs0 = rss[4 * qd], rs1 = rss[4 * qd + 1], rs2 = rss[4 * qd + 2], rs3 = rss[4 * qd + 3];
    u16* dp = &dst[(l * HD + hg * 16) * BB + 4 * qd];
#pragma unroll
    for (int k = 0; k < 16; k++) {
        float g = gs[hg * 16 + k], b = bs[hg * 16 + k];
        u4h w;
        w[0] = (u16)f2b(fmaf((v[4 * k + 0] - mu0) * rs0, g, b));
        w[1] = (u16)f2b(fmaf((v[4 * k + 1] - mu1) * rs1, g, b));
        w[2] = (u16)f2b(fmaf((v[4 * k + 2] - mu2) * rs2, g, b));
        w[3] = (u16)f2b(fmaf((v[4 * k + 3] - mu3) * rs3, g, b));
        *(u4h*)(dp + (size_t)k * BB) = w;
    }
}

// ---------------------------------------------------------------------------
// Mean-pool over l from bf16 Vb: PO[h*64+b] = mean_l Vb[l][h][b].
// ---------------------------------------------------------------------------
__global__ void pool_k(const u16* __restrict__ Vb, float* __restrict__ PO)
{
    __shared__ float red[4][64];
    int h = blockIdx.x;
    int b = threadIdx.x & 63;
    int lg = threadIdx.x >> 6;               // 0..3
    const u16* p = &Vb[(size_t)h * BB + b];
    float s = 0.f;
    for (int l = lg; l < LSEQ; l += 4) s += b2f16(p[(size_t)l * HD * BB]);
    red[lg][b] = s;
    __syncthreads();
    if (threadIdx.x < 64) {
        float t = red[0][b] + red[1][b] + red[2][b] + red[3][b];
        PO[h * BB + b] = t * (1.0f / LSEQ);
    }
}

// ---------------------------------------------------------------------------
// Decoder: out[b,c] = PO[:,b] . dec_w[:,c] + dec_b[c]
// ---------------------------------------------------------------------------
__global__ void dec_k(const float* __restrict__ PO, const float* __restrict__ w,
                      const float* __restrict__ bias, float* __restrict__ out)
{
    int t = blockIdx.x * 256 + threadIdx.x;
    if (t >= BB * 10) return;
    int cc = t % 10, b = t / 10;
    float acc = bias[cc];
    for (int hh = 0; hh < HD; hh++)
        acc = fmaf(PO[hh * BB + b], w[hh * 10 + cc], acc);
    out[t] = acc;
}

// ---------------------------------------------------------------------------
extern "C" void kernel_launch(void* const* d_in, const int* in_sizes, int n_in,
                              void* d_out, int out_size, void* d_ws, size_t ws_size,
                              hipStream_t stream)
{
    const float* x   = (const float*)d_in[0];
    const float* ew  = (const float*)d_in[1];
    const float* eb  = (const float*)d_in[2];
    const float* ldt = (const float*)d_in[3];
    const float* lar = (const float*)d_in[4];
    const float* aim = (const float*)d_in[5];
    const float* cre = (const float*)d_in[6];
    const float* cim = (const float*)d_in[7];
    const float* Dp  = (const float*)d_in[8];
    const float* lng = (const float*)d_in[9];
    const float* lnb = (const float*)d_in[10];
    const float* fng = (const float*)d_in[11];
    const float* fnb = (const float*)d_in[12];
    const float* dw  = (const float*)d_in[13];
    const float* db  = (const float*)d_in[14];
    float* out = (float*)d_out;

    const size_t SZ  = (size_t)BB * LSEQ * HD;       // 25,690,112 elems
    const size_t SZB = (size_t)BB * LPADROWS * HD;   // 26,214,400 u16 slots
    const size_t PP  = (size_t)NLAY * HD * NST;      // 196,608
    u16*   Vb  = (u16*)d_ws;                // bf16 residual stream [l][h][b]
    u16*   V2  = Vb + SZB;                  // bf16 pre-LN buffer
    float* PAR = (float*)(V2 + SZ);
    float* lamr = PAR,        * lami = PAR + PP;
    float* dtr  = PAR + 2*PP, * dti  = PAR + 3*PP;
    float* c2r  = PAR + 4*PP, * c2i  = PAR + 5*PP;
    u16* KA = (u16*)(PAR + 6 * PP);                  // 6*512*848 u16
    float* PO = PAR + 6 * PP + (NLAY * HD * NKA) / 2;
    // total ~116 MB

    precompute_k<<<(NLAY * HD * NST + 255) / 256, 256, 0, stream>>>(
        ldt, lar, aim, cre, cim, lamr, lami, dtr, dti, c2r, c2i);
    kq_k<<<(NLAY * HD * 49) / 256, 256, 0, stream>>>(
        lamr, lami, dtr, dti, c2r, c2i, KA);
    encoder_k<<<(int)(SZ / 256), 256, 0, stream>>>(x, ew, eb, Vb);

    for (int i = 0; i < NLAY; i++) {
        conv_k<<<512 * CHK, 256, 0, stream>>>(
            Vb, V2, KA + (size_t)i * HD * NKA, Dp + i * HD);
        lnT_k<<<LSEQ, 512, 0, stream>>>(V2, Vb, lng + i * HD, lnb + i * HD);
    }
    lnT_k<<<LSEQ, 512, 0, stream>>>(Vb, Vb, fng, fnb);  // final LN in place
    pool_k<<<HD, 256, 0, stream>>>(Vb, PO);
    dec_k<<<(BB * 10 + 255) / 256, 256, 0, stream>>>(PO, dw, db, out);
}

// Round 14
// 655.006 us; speedup vs baseline: 1.5674x; 1.0968x over previous
//
#include <hip/hip_runtime.h>
#include <hip/hip_bf16.h>

#define HD 512      // d_model
#define NST 64      // d_state
#define NLAY 6
#define LSEQ 784
#define BB 64       // batch
#define NKA 848     // reversed+padded kernel array length (u16)
#define TOFF 800    // KA[t] = K[TOFF - t]; t in [17,800] real, else 0
#define LPADROWS 800  // padded L (25 tiles of 32); pad rows killed by zero-K
#define KSTR 850    // u16 stride between shifted K copies (dword 425 == 9 mod 32)
#define CHK2 5      // 32-row l-tiles per conv block; 25 = 5*5
#define NCH 5       // chunks
#define UTS2 9      // UT row stride in dwords (8 j-pairs + 1 pad)

typedef unsigned short u16;
typedef short s8v __attribute__((ext_vector_type(8)));   // 8 bf16 (4 VGPR)
typedef float f16v __attribute__((ext_vector_type(16))); // 32x32 MFMA acc
typedef u16  u4h __attribute__((ext_vector_type(4)));    // ushort4 (8B)

// fp32 -> bf16 bits, round-to-nearest-even
__device__ __forceinline__ unsigned f2b(float f)
{
    unsigned u = __builtin_bit_cast(unsigned, f);
    return (u + 0x7FFFu + ((u >> 16) & 1u)) >> 16;
}
__device__ __forceinline__ float b2f16(u16 v)
{
    unsigned u = ((unsigned)v) << 16;
    return __builtin_bit_cast(float, u);
}

// ---------------------------------------------------------------------------
// Per (layer,h,n): lambda = exp(dt*A), dtA, 2*Cd. Layout [i][h][n].
// ---------------------------------------------------------------------------
__global__ void precompute_k(const float* __restrict__ log_dt,
                             const float* __restrict__ log_A_real,
                             const float* __restrict__ A_imag,
                             const float* __restrict__ C_re,
                             const float* __restrict__ C_im,
                             float* __restrict__ lamr, float* __restrict__ lami,
                             float* __restrict__ dtr,  float* __restrict__ dti,
                             float* __restrict__ c2r,  float* __restrict__ c2i)
{
    int t = blockIdx.x * 256 + threadIdx.x;
    if (t >= NLAY * HD * NST) return;
    int ih = t >> 6;                       // i*HD + h
    float dt  = expf(log_dt[ih]);
    float are = -expf(log_A_real[t]);
    float aim = A_imag[t];
    float dr = are * dt, di = aim * dt;
    float er = expf(dr);
    float sn, cs; __sincosf(di, &sn, &cs);
    float lr = er * cs, li = er * sn;      // lambda
    float e1r = lr - 1.0f, e1i = li;
    float den = are * are + aim * aim;
    float qr = (e1r * are + e1i * aim) / den;
    float qi = (e1i * are - e1r * aim) / den;
    float crv = C_re[t], civ = C_im[t];
    lamr[t] = lr; lami[t] = li; dtr[t] = dr; dti[t] = di;
    c2r[t] = 2.0f * (crv * qr - civ * qi);
    c2i[t] = 2.0f * (crv * qi + civ * qr);
}

// ---------------------------------------------------------------------------
// Build KA[i][h][t] (bf16): reversed, zero-padded conv kernel.
// KA[TOFF - d] = K[d], d = 0..783; all other slots zero.
// ---------------------------------------------------------------------------
__global__ void kq_k(const float* __restrict__ lamr, const float* __restrict__ lami,
                     const float* __restrict__ dtr,  const float* __restrict__ dti,
                     const float* __restrict__ c2r,  const float* __restrict__ c2i,
                     u16* __restrict__ KA)
{
    int t = blockIdx.x * 256 + threadIdx.x;   // < 6*512*49
    int dc = t % 49;
    int ih = t / 49;                          // i*HD + h
    int d0 = dc * 16;
    float acc[16];
#pragma unroll
    for (int k = 0; k < 16; k++) acc[k] = 0.f;
    int base = ih * 64;
    for (int n = 0; n < 64; n++) {
        float lr = lamr[base + n], li = lami[base + n];
        float dr = dtr[base + n],  di = dti[base + n];
        float cr = c2r[base + n],  ci = c2i[base + n];
        float e = __expf(dr * (float)d0);
        float sn, cs; __sincosf(di * (float)d0, &sn, &cs);
        float pr = e * cs, pi = e * sn;       // lam^d0
#pragma unroll
        for (int k = 0; k < 16; k++) {
            acc[k] = fmaf(cr, pr, fmaf(-ci, pi, acc[k]));
            float nr = pr * lr - pi * li;
            pi = fmaf(pr, li, pi * lr);
            pr = nr;
        }
    }
    u16* kap = KA + (size_t)ih * NKA;
#pragma unroll
    for (int k = 0; k < 16; k++)
        kap[TOFF - (d0 + k)] = (u16)f2b(acc[k]);
    if (dc == 0)  for (int z = TOFF + 1; z < NKA; z++) kap[z] = 0;
    if (dc == 48) for (int z = 0; z < TOFF - 783; z++) kap[z] = 0;
}

// ---------------------------------------------------------------------------
// Encoder into bf16 [l][h][b]: Vb = bf16(x[b,l]*ew[h]+eb[h])
// ---------------------------------------------------------------------------
__global__ void encoder_k(const float* __restrict__ x, const float* __restrict__ ew,
                          const float* __restrict__ eb, u16* __restrict__ Vb)
{
    size_t g = (size_t)blockIdx.x * 256 + threadIdx.x;
    int b = (int)(g & 63);
    int h = (int)((g >> 6) & 511);
    int l = (int)(g >> 15);
    Vb[g] = (u16)f2b(fmaf(x[b * LSEQ + l], ew[h], eb[h]));
}

// ---------------------------------------------------------------------------
// MFMA causal-Toeplitz conv + residual via 32x32x16 bf16 MFMA.
// Block = 128 thr = (h, chunk c of 5 32-row l-tiles) x 2 waves (b-halves).
// 32x32 halves A/B LDS bytes and MFMA count per FLOP vs 16x16x32.
// A[m][k]: m=lane&31, k=8*(lane>>5)+j, from 8 lane-shifted K copies
// (16B-aligned: 850s - s - s == 0 mod 8) -> 1 ds_read_b128 per frag.
// B[k][n]: n=lane&31, k=8*(lane>>5)+j; tile 16j x 64b staged as j-pair
// dwords, UT stride 9 (reads/writes <=2-way banks).
// C/D layout (measured m74/m101): col=lane&31, row=(reg&3)+8*(reg>>2)
// +4*(lane>>5). L padded to 800; pad rows hit only zero-K (t>800 region).
// One barrier per 16-j step; next tile's global loads issued pre-compute.
// ---------------------------------------------------------------------------
__global__ __launch_bounds__(128, 4)
void conv_k(const u16* __restrict__ Vb, u16* __restrict__ V2,
            const u16* __restrict__ KA, const float* __restrict__ Dvec)
{
    __shared__ __align__(16) u16 KR[6816];           // 8 shifted copies
    __shared__ __align__(16) unsigned UT[2][64 * UTS2];

    const int thr = threadIdx.x;
    const int h   = blockIdx.x & 511;
    const int c   = blockIdx.x >> 9;         // 0..4
    const int w   = thr >> 6;                // b-half (n-tile)
    const int lane = thr & 63;
    const int n2 = lane & 31;
    const int qp = lane >> 5;
    const int JTN = 10 * c + 10;

    // stage 8 shifted copies: KR[KSTR*s + ((8-s)&7) + i] = kap[i]
    const u16* kap = KA + (size_t)h * NKA;
    {
        int s = thr & 7, ch = thr >> 3;      // 16 chunks x 53 (covers 848)
        int i0 = ch * 53;
        int i1 = (i0 + 53 < NKA) ? (i0 + 53) : NKA;
        u16* kr = KR + KSTR * s + ((8 - s) & 7);
        for (int i = i0; i < i1; i++) kr[i] = kap[i];
    }

    // B staging: thread = (jj = j-pair 0..7, bq = b-quad 0..15)
    const int jj = thr >> 4;
    const int bq = thr & 15;
    {   // stage tile jt=0 (j rows 0..15)
        const u16* p = &Vb[((size_t)(2 * jj) * HD + h) * BB + 4 * bq];
        u4h r0 = *(const u4h*)p;
        u4h r1 = *(const u4h*)(p + (size_t)HD * BB);
        unsigned* up = &UT[0][0];
#pragma unroll
        for (int i = 0; i < 4; i++)
            up[(4 * bq + i) * UTS2 + jj] = (unsigned)r0[i] | ((unsigned)r1[i] << 16);
    }
    __syncthreads();

    f16v acc[CHK2];
#pragma unroll
    for (int i = 0; i < CHK2; i++)
#pragma unroll
        for (int r = 0; r < 16; r++) acc[i][r] = 0.f;

    const float dcoef = 1.0f + Dvec[h];

    // per-lane A base: copy s=lane&7; addr(lt,jt) = krb + 16*jt - 32*lt
    const int s = lane & 7;
    const u16* krb = KR + KSTR * s + ((8 - s) & 7)
                     + (TOFF - 160 * c) + 8 * qp - n2;
    // B-frag base pointers (per buffer)
    const unsigned* bb0 = &UT[0][(32 * w + n2) * UTS2 + 4 * qp];
    const unsigned* bb1 = &UT[1][(32 * w + n2) * UTS2 + 4 * qp];

    for (int jt = 0; jt < JTN; ++jt) {
        // issue next tile's global loads (consumed after compute)
        u4h r0, r1;
        const bool more = (jt + 1) < JTN;
        if (more) {
            int j = 16 * (jt + 1) + 2 * jj;  // rows <= 799 (slack), zero-K kills pads
            const u16* p = &Vb[((size_t)j * HD + h) * BB + 4 * bq];
            r0 = *(const u4h*)p;
            r1 = *(const u4h*)(p + (size_t)HD * BB);
        }
        // B fragment (same for all l-tiles this step)
        const unsigned* bb = (jt & 1) ? bb1 : bb0;
        union { unsigned u[4]; s8v v; } bu;
        bu.u[0] = bb[0]; bu.u[1] = bb[1]; bu.u[2] = bb[2]; bu.u[3] = bb[3];

        const u16* ap0 = krb + 16 * jt;
#pragma unroll
        for (int lt = 0; lt < CHK2; ++lt) {
            if (jt > 10 * c + 2 * lt + 1) continue;   // tile done (uniform)
            s8v av = *(const s8v*)__builtin_assume_aligned(ap0 - 32 * lt, 16);
            acc[lt] = __builtin_amdgcn_mfma_f32_32x32x16_bf16(av, bu.v, acc[lt], 0, 0, 0);
        }
        if (more) {
            unsigned* up = &UT[(jt & 1) ^ 1][0];
#pragma unroll
            for (int i = 0; i < 4; i++)
                up[(4 * bq + i) * UTS2 + jj] = (unsigned)r0[i] | ((unsigned)r1[i] << 16);
        }
        __syncthreads();
    }

    // epilogue: V2 = bf16(y + (1+D)*u)  (pre-LN residual)
#pragma unroll
    for (int lt = 0; lt < CHK2; ++lt) {
        const int l0 = 32 * (5 * c + lt) + 4 * qp;
#pragma unroll
        for (int r = 0; r < 16; ++r) {
            int l = l0 + (r & 3) + 8 * (r >> 2);
            size_t a = ((size_t)l * HD + h) * BB + 32 * w + n2;
            V2[a] = (u16)f2b(fmaf(dcoef, b2f16(Vb[a]), acc[lt][r]));
        }
    }
}

// ---------------------------------------------------------------------------
// LayerNorm over h in [l][h][b]; bf16 in/out, fp32 math, u4h-vectorized.
// Block = one l, 512 thr: thread (qd = b-quad, hg = h-group of 16).
// ---------------------------------------------------------------------------
__global__ __launch_bounds__(512)
void lnT_k(const u16* __restrict__ src, u16* __restrict__ dst,
           const float* __restrict__ gp, const float* __restrict__ bp)
{
    __shared__ float redS[32][68], redQ[32][68];
    __shared__ float mus[64], rss[64];
    __shared__ float gs[512], bs[512];
    const int thr = threadIdx.x;
    const int qd = thr & 15;          // b-quad (b = 4*qd + i)
    const int hg = thr >> 4;          // 0..31 (h = hg*16 + k)
    const size_t l = blockIdx.x;
    gs[thr] = gp[thr]; bs[thr] = bp[thr];

    const u16* sp = &src[(l * HD + hg * 16) * BB + 4 * qd];
    float v[64];
    float s0 = 0, s1 = 0, s2 = 0, s3 = 0, q0 = 0, q1 = 0, q2 = 0, q3 = 0;
#pragma unroll
    for (int k = 0; k < 16; k++) {
        u4h r = *(const u4h*)(sp + (size_t)k * BB);
        float x0 = b2f16(r[0]), x1 = b2f16(r[1]);
        float x2 = b2f16(r[2]), x3 = b2f16(r[3]);
        v[4 * k + 0] = x0; v[4 * k + 1] = x1; v[4 * k + 2] = x2; v[4 * k + 3] = x3;
        s0 += x0; s1 += x1; s2 += x2; s3 += x3;
        q0 = fmaf(x0, x0, q0); q1 = fmaf(x1, x1, q1);
        q2 = fmaf(x2, x2, q2); q3 = fmaf(x3, x3, q3);
    }
    redS[hg][4 * qd + 0] = s0; redS[hg][4 * qd + 1] = s1;
    redS[hg][4 * qd + 2] = s2; redS[hg][4 * qd + 3] = s3;
    redQ[hg][4 * qd + 0] = q0; redQ[hg][4 * qd + 1] = q1;
    redQ[hg][4 * qd + 2] = q2; redQ[hg][4 * qd + 3] = q3;
    __syncthreads();
    if (thr < 64) {
        float ts = 0.f, tq = 0.f;
#pragma unroll
        for (int g = 0; g < 32; g++) { ts += redS[g][thr]; tq += redQ[g][thr]; }
        float mu = ts * (1.0f / HD);
        mus[thr] = mu;
        rss[thr] = rsqrtf(tq * (1.0f / HD) - mu * mu + 1e-5f);
    }
    __syncthreads();
    float mu0 = mus[4 * qd], mu1 = mus[4 * qd + 1], mu2 = mus[4 * qd + 2], mu3 = mus[4 * qd + 3];
    float rs0 = rss[4 * qd], rs1 = rss[4 * qd + 1], rs2 = rss[4 * qd + 2], rs3 = rss[4 * qd + 3];
    u16* dp = &dst[(l * HD + hg * 16) * BB + 4 * qd];
#pragma unroll
    for (int k = 0; k < 16; k++) {
        float g = gs[hg * 16 + k], b = bs[hg * 16 + k];
        u4h w;
        w[0] = (u16)f2b(fmaf((v[4 * k + 0] - mu0) * rs0, g, b));
        w[1] = (u16)f2b(fmaf((v[4 * k + 1] - mu1) * rs1, g, b));
        w[2] = (u16)f2b(fmaf((v[4 * k + 2] - mu2) * rs2, g, b));
        w[3] = (u16)f2b(fmaf((v[4 * k + 3] - mu3) * rs3, g, b));
        *(u4h*)(dp + (size_t)k * BB) = w;
    }
}

// ---------------------------------------------------------------------------
// Mean-pool over l from bf16 Vb: PO[h*64+b] = mean_l Vb[l][h][b].
// ---------------------------------------------------------------------------
__global__ void pool_k(const u16* __restrict__ Vb, float* __restrict__ PO)
{
    __shared__ float red[4][64];
    int h = blockIdx.x;
    int b = threadIdx.x & 63;
    int lg = threadIdx.x >> 6;               // 0..3
    const u16* p = &Vb[(size_t)h * BB + b];
    float s = 0.f;
    for (int l = lg; l < LSEQ; l += 4) s += b2f16(p[(size_t)l * HD * BB]);
    red[lg][b] = s;
    __syncthreads();
    if (threadIdx.x < 64) {
        float t = red[0][b] + red[1][b] + red[2][b] + red[3][b];
        PO[h * BB + b] = t * (1.0f / LSEQ);
    }
}

// ---------------------------------------------------------------------------
// Decoder: out[b,c] = PO[:,b] . dec_w[:,c] + dec_b[c]
// ---------------------------------------------------------------------------
__global__ void dec_k(const float* __restrict__ PO, const float* __restrict__ w,
                      const float* __restrict__ bias, float* __restrict__ out)
{
    int t = blockIdx.x * 256 + threadIdx.x;
    if (t >= BB * 10) return;
    int cc = t % 10, b = t / 10;
    float acc = bias[cc];
    for (int hh = 0; hh < HD; hh++)
        acc = fmaf(PO[hh * BB + b], w[hh * 10 + cc], acc);
    out[t] = acc;
}

// ---------------------------------------------------------------------------
extern "C" void kernel_launch(void* const* d_in, const int* in_sizes, int n_in,
                              void* d_out, int out_size, void* d_ws, size_t ws_size,
                              hipStream_t stream)
{
    const float* x   = (const float*)d_in[0];
    const float* ew  = (const float*)d_in[1];
    const float* eb  = (const float*)d_in[2];
    const float* ldt = (const float*)d_in[3];
    const float* lar = (const float*)d_in[4];
    const float* aim = (const float*)d_in[5];
    const float* cre = (const float*)d_in[6];
    const float* cim = (const float*)d_in[7];
    const float* Dp  = (const float*)d_in[8];
    const float* lng = (const float*)d_in[9];
    const float* lnb = (const float*)d_in[10];
    const float* fng = (const float*)d_in[11];
    const float* fnb = (const float*)d_in[12];
    const float* dw  = (const float*)d_in[13];
    const float* db  = (const float*)d_in[14];
    float* out = (float*)d_out;

    const size_t SZ  = (size_t)BB * LSEQ * HD;       // 25,690,112 elems
    const size_t SZB = (size_t)BB * LPADROWS * HD;   // 26,214,400 u16 slots
    const size_t PP  = (size_t)NLAY * HD * NST;      // 196,608
    u16*   Vb  = (u16*)d_ws;                // bf16 residual stream [l][h][b]
    u16*   V2  = Vb + SZB;                  // bf16 pre-LN buffer (w/ slack)
    float* PAR = (float*)(V2 + SZB);
    float* lamr = PAR,        * lami = PAR + PP;
    float* dtr  = PAR + 2*PP, * dti  = PAR + 3*PP;
    float* c2r  = PAR + 4*PP, * c2i  = PAR + 5*PP;
    u16* KA = (u16*)(PAR + 6 * PP);                  // 6*512*848 u16
    float* PO = PAR + 6 * PP + (NLAY * HD * NKA) / 2;
    // total ~116 MB

    precompute_k<<<(NLAY * HD * NST + 255) / 256, 256, 0, stream>>>(
        ldt, lar, aim, cre, cim, lamr, lami, dtr, dti, c2r, c2i);
    kq_k<<<(NLAY * HD * 49) / 256, 256, 0, stream>>>(
        lamr, lami, dtr, dti, c2r, c2i, KA);
    encoder_k<<<(int)(SZ / 256), 256, 0, stream>>>(x, ew, eb, Vb);

    for (int i = 0; i < NLAY; i++) {
        conv_k<<<512 * NCH, 128, 0, stream>>>(
            Vb, V2, KA + (size_t)i * HD * NKA, Dp + i * HD);
        lnT_k<<<LSEQ, 512, 0, stream>>>(V2, Vb, lng + i * HD, lnb + i * HD);
    }
    lnT_k<<<LSEQ, 512, 0, stream>>>(Vb, Vb, fng, fnb);  // final LN in place
    pool_k<<<HD, 256, 0, stream>>>(Vb, PO);
    dec_k<<<(BB * 10 + 255) / 256, 256, 0, stream>>>(PO, dw, db, out);
}

// Round 15
// 625.572 us; speedup vs baseline: 1.6412x; 1.0471x over previous
//
#include <hip/hip_runtime.h>
#include <hip/hip_bf16.h>

#define HD 512      // d_model
#define NST 64      // d_state
#define NLAY 6
#define LSEQ 784
#define BB 64       // batch
#define NKA 848     // reversed+padded kernel array length (u16)
#define TOFF 800    // KA[t] = K[TOFF - t]; t in [17,800] real, else 0
#define LPADROWS 800  // padded L (25 tiles of 32); pad rows killed by zero-K
#define KSTR 850    // u16 stride between shifted K copies
#define CHK2 5      // 32-row l-tiles per conv block; 25 = 5*5
#define NCH 5       // chunks
#define UTS2 9      // UT row stride in dwords (8 j-pairs + 1 pad)

typedef unsigned short u16;
typedef short s8v __attribute__((ext_vector_type(8)));   // 8 bf16 (4 VGPR)
typedef float f16v __attribute__((ext_vector_type(16))); // 32x32 MFMA acc
typedef u16  u4h __attribute__((ext_vector_type(4)));    // ushort4 (8B)
typedef u16  u8h __attribute__((ext_vector_type(8)));    // ushort8 (16B)

// fp32 -> bf16 bits, round-to-nearest-even
__device__ __forceinline__ unsigned f2b(float f)
{
    unsigned u = __builtin_bit_cast(unsigned, f);
    return (u + 0x7FFFu + ((u >> 16) & 1u)) >> 16;
}
__device__ __forceinline__ float b2f16(u16 v)
{
    unsigned u = ((unsigned)v) << 16;
    return __builtin_bit_cast(float, u);
}

// ---------------------------------------------------------------------------
// Per (layer,h,n): lambda = exp(dt*A), dtA, 2*Cd. Layout [i][h][n].
// ---------------------------------------------------------------------------
__global__ void precompute_k(const float* __restrict__ log_dt,
                             const float* __restrict__ log_A_real,
                             const float* __restrict__ A_imag,
                             const float* __restrict__ C_re,
                             const float* __restrict__ C_im,
                             float* __restrict__ lamr, float* __restrict__ lami,
                             float* __restrict__ dtr,  float* __restrict__ dti,
                             float* __restrict__ c2r,  float* __restrict__ c2i)
{
    int t = blockIdx.x * 256 + threadIdx.x;
    if (t >= NLAY * HD * NST) return;
    int ih = t >> 6;                       // i*HD + h
    float dt  = expf(log_dt[ih]);
    float are = -expf(log_A_real[t]);
    float aim = A_imag[t];
    float dr = are * dt, di = aim * dt;
    float er = expf(dr);
    float sn, cs; __sincosf(di, &sn, &cs);
    float lr = er * cs, li = er * sn;      // lambda
    float e1r = lr - 1.0f, e1i = li;
    float den = are * are + aim * aim;
    float qr = (e1r * are + e1i * aim) / den;
    float qi = (e1i * are - e1r * aim) / den;
    float crv = C_re[t], civ = C_im[t];
    lamr[t] = lr; lami[t] = li; dtr[t] = dr; dti[t] = di;
    c2r[t] = 2.0f * (crv * qr - civ * qi);
    c2i[t] = 2.0f * (crv * qi + civ * qr);
}

// ---------------------------------------------------------------------------
// Build KA[i][h][t] (bf16): reversed, zero-padded conv kernel.
// ---------------------------------------------------------------------------
__global__ void kq_k(const float* __restrict__ lamr, const float* __restrict__ lami,
                     const float* __restrict__ dtr,  const float* __restrict__ dti,
                     const float* __restrict__ c2r,  const float* __restrict__ c2i,
                     u16* __restrict__ KA)
{
    int t = blockIdx.x * 256 + threadIdx.x;   // < 6*512*49
    int dc = t % 49;
    int ih = t / 49;                          // i*HD + h
    int d0 = dc * 16;
    float acc[16];
#pragma unroll
    for (int k = 0; k < 16; k++) acc[k] = 0.f;
    int base = ih * 64;
    for (int n = 0; n < 64; n++) {
        float lr = lamr[base + n], li = lami[base + n];
        float dr = dtr[base + n],  di = dti[base + n];
        float cr = c2r[base + n],  ci = c2i[base + n];
        float e = __expf(dr * (float)d0);
        float sn, cs; __sincosf(di * (float)d0, &sn, &cs);
        float pr = e * cs, pi = e * sn;       // lam^d0
#pragma unroll
        for (int k = 0; k < 16; k++) {
            acc[k] = fmaf(cr, pr, fmaf(-ci, pi, acc[k]));
            float nr = pr * lr - pi * li;
            pi = fmaf(pr, li, pi * lr);
            pr = nr;
        }
    }
    u16* kap = KA + (size_t)ih * NKA;
#pragma unroll
    for (int k = 0; k < 16; k++)
        kap[TOFF - (d0 + k)] = (u16)f2b(acc[k]);
    if (dc == 0)  for (int z = TOFF + 1; z < NKA; z++) kap[z] = 0;
    if (dc == 48) for (int z = 0; z < TOFF - 783; z++) kap[z] = 0;
}

// ---------------------------------------------------------------------------
// Transpose x[b][l] -> xT[l][b] (200 KB, L2-resident; cost ~2 us)
// ---------------------------------------------------------------------------
__global__ void xt_k(const float* __restrict__ x, float* __restrict__ xT)
{
    int t = blockIdx.x * 256 + threadIdx.x;   // < 784*64
    int l = t >> 6, b = t & 63;
    xT[t] = x[b * LSEQ + l];
}

// ---------------------------------------------------------------------------
// Encoder v2: thread = (l, h, b-oct). Reads 8 fp32 from xT (coalesced),
// writes 8 packed bf16 (uint4, 16B) -> 1KB/wave contiguous stores.
// ---------------------------------------------------------------------------
__global__ void encoder_k(const float* __restrict__ xT, const float* __restrict__ ew,
                          const float* __restrict__ eb, u16* __restrict__ Vb)
{
    int g = blockIdx.x * 256 + threadIdx.x;   // < 784*512*8
    int bo = g & 7;
    int h  = (g >> 3) & 511;
    int l  = g >> 12;
    const float4* xp = (const float4*)&xT[l * BB + 8 * bo];
    float4 a0 = xp[0], a1 = xp[1];
    float w = ew[h], bb = eb[h];
    unsigned p0 = f2b(fmaf(a0.x, w, bb)) | (f2b(fmaf(a0.y, w, bb)) << 16);
    unsigned p1 = f2b(fmaf(a0.z, w, bb)) | (f2b(fmaf(a0.w, w, bb)) << 16);
    unsigned p2 = f2b(fmaf(a1.x, w, bb)) | (f2b(fmaf(a1.y, w, bb)) << 16);
    unsigned p3 = f2b(fmaf(a1.z, w, bb)) | (f2b(fmaf(a1.w, w, bb)) << 16);
    *(uint4*)&Vb[((size_t)l * HD + h) * BB + 8 * bo] = (uint4){p0, p1, p2, p3};
}

// ---------------------------------------------------------------------------
// MFMA causal-Toeplitz conv + residual via 32x32x16 bf16 MFMA.
// (unchanged from round 14 — see comments there)
// ---------------------------------------------------------------------------
__global__ __launch_bounds__(128, 4)
void conv_k(const u16* __restrict__ Vb, u16* __restrict__ V2,
            const u16* __restrict__ KA, const float* __restrict__ Dvec)
{
    __shared__ __align__(16) u16 KR[6816];           // 8 shifted copies
    __shared__ __align__(16) unsigned UT[2][64 * UTS2];

    const int thr = threadIdx.x;
    const int h   = blockIdx.x & 511;
    const int c   = blockIdx.x >> 9;         // 0..4
    const int w   = thr >> 6;                // b-half (n-tile)
    const int lane = thr & 63;
    const int n2 = lane & 31;
    const int qp = lane >> 5;
    const int JTN = 10 * c + 10;

    const u16* kap = KA + (size_t)h * NKA;
    {
        int s = thr & 7, ch = thr >> 3;      // 16 chunks x 53 (covers 848)
        int i0 = ch * 53;
        int i1 = (i0 + 53 < NKA) ? (i0 + 53) : NKA;
        u16* kr = KR + KSTR * s + ((8 - s) & 7);
        for (int i = i0; i < i1; i++) kr[i] = kap[i];
    }

    const int jj = thr >> 4;
    const int bq = thr & 15;
    {   // stage tile jt=0 (j rows 0..15)
        const u16* p = &Vb[((size_t)(2 * jj) * HD + h) * BB + 4 * bq];
        u4h r0 = *(const u4h*)p;
        u4h r1 = *(const u4h*)(p + (size_t)HD * BB);
        unsigned* up = &UT[0][0];
#pragma unroll
        for (int i = 0; i < 4; i++)
            up[(4 * bq + i) * UTS2 + jj] = (unsigned)r0[i] | ((unsigned)r1[i] << 16);
    }
    __syncthreads();

    f16v acc[CHK2];
#pragma unroll
    for (int i = 0; i < CHK2; i++)
#pragma unroll
        for (int r = 0; r < 16; r++) acc[i][r] = 0.f;

    const float dcoef = 1.0f + Dvec[h];

    const int s = lane & 7;
    const u16* krb = KR + KSTR * s + ((8 - s) & 7)
                     + (TOFF - 160 * c) + 8 * qp - n2;
    const unsigned* bb0 = &UT[0][(32 * w + n2) * UTS2 + 4 * qp];
    const unsigned* bb1 = &UT[1][(32 * w + n2) * UTS2 + 4 * qp];

    for (int jt = 0; jt < JTN; ++jt) {
        u4h r0, r1;
        const bool more = (jt + 1) < JTN;
        if (more) {
            int j = 16 * (jt + 1) + 2 * jj;
            const u16* p = &Vb[((size_t)j * HD + h) * BB + 4 * bq];
            r0 = *(const u4h*)p;
            r1 = *(const u4h*)(p + (size_t)HD * BB);
        }
        const unsigned* bb = (jt & 1) ? bb1 : bb0;
        union { unsigned u[4]; s8v v; } bu;
        bu.u[0] = bb[0]; bu.u[1] = bb[1]; bu.u[2] = bb[2]; bu.u[3] = bb[3];

        const u16* ap0 = krb + 16 * jt;
#pragma unroll
        for (int lt = 0; lt < CHK2; ++lt) {
            if (jt > 10 * c + 2 * lt + 1) continue;   // tile done (uniform)
            s8v av = *(const s8v*)__builtin_assume_aligned(ap0 - 32 * lt, 16);
            acc[lt] = __builtin_amdgcn_mfma_f32_32x32x16_bf16(av, bu.v, acc[lt], 0, 0, 0);
        }
        if (more) {
            unsigned* up = &UT[(jt & 1) ^ 1][0];
#pragma unroll
            for (int i = 0; i < 4; i++)
                up[(4 * bq + i) * UTS2 + jj] = (unsigned)r0[i] | ((unsigned)r1[i] << 16);
        }
        __syncthreads();
    }

    // epilogue: V2 = bf16(y + (1+D)*u)
#pragma unroll
    for (int lt = 0; lt < CHK2; ++lt) {
        const int l0 = 32 * (5 * c + lt) + 4 * qp;
#pragma unroll
        for (int r = 0; r < 16; ++r) {
            int l = l0 + (r & 3) + 8 * (r >> 2);
            size_t a = ((size_t)l * HD + h) * BB + 32 * w + n2;
            V2[a] = (u16)f2b(fmaf(dcoef, b2f16(Vb[a]), acc[lt][r]));
        }
    }
}

// ---------------------------------------------------------------------------
// LayerNorm v2 over h in [l][h][b]; bf16 in/out, fp32 math, u8h (16B) I/O.
// Block = one l, 512 thr: thread (bo = b-oct 0..7, hg = h-group-of-8 0..63).
// LDS reduction rows padded to 65 (banks <=2-way).
// ---------------------------------------------------------------------------
__global__ __launch_bounds__(512)
void lnT_k(const u16* __restrict__ src, u16* __restrict__ dst,
           const float* __restrict__ gp, const float* __restrict__ bp)
{
    __shared__ float redS[64][65], redQ[64][65];
    __shared__ float mus[64], rss[64];
    __shared__ float gs[512], bs[512];
    const int thr = threadIdx.x;
    const int bo = thr & 7;           // b = 8*bo + i
    const int hg = thr >> 3;          // h = 8*hg + k
    const size_t l = blockIdx.x;
    gs[thr] = gp[thr]; bs[thr] = bp[thr];

    const u16* sp = &src[(l * HD + hg * 8) * BB + 8 * bo];
    float v[64];                       // v[k*8+i]
    float s[8] = {0, 0, 0, 0, 0, 0, 0, 0};
    float q[8] = {0, 0, 0, 0, 0, 0, 0, 0};
#pragma unroll
    for (int k = 0; k < 8; k++) {
        u8h r = *(const u8h*)(sp + (size_t)k * BB);
#pragma unroll
        for (int i = 0; i < 8; i++) {
            float x = b2f16(r[i]);
            v[k * 8 + i] = x;
            s[i] += x;
            q[i] = fmaf(x, x, q[i]);
        }
    }
#pragma unroll
    for (int i = 0; i < 8; i++) { redS[hg][8 * bo + i] = s[i]; redQ[hg][8 * bo + i] = q[i]; }
    __syncthreads();
    if (thr < 64) {
        float ts = 0.f, tq = 0.f;
#pragma unroll
        for (int g = 0; g < 64; g++) { ts += redS[g][thr]; tq += redQ[g][thr]; }
        float mu = ts * (1.0f / HD);
        mus[thr] = mu;
        rss[thr] = rsqrtf(tq * (1.0f / HD) - mu * mu + 1e-5f);
    }
    __syncthreads();
    float mu[8], rs[8];
#pragma unroll
    for (int i = 0; i < 8; i++) { mu[i] = mus[8 * bo + i]; rs[i] = rss[8 * bo + i]; }
    u16* dp = &dst[(l * HD + hg * 8) * BB + 8 * bo];
#pragma unroll
    for (int k = 0; k < 8; k++) {
        float g = gs[hg * 8 + k], bb = bs[hg * 8 + k];
        u8h w;
#pragma unroll
        for (int i = 0; i < 8; i++)
            w[i] = (u16)f2b(fmaf((v[k * 8 + i] - mu[i]) * rs[i], g, bb));
        *(u8h*)(dp + (size_t)k * BB) = w;
    }
}

// ---------------------------------------------------------------------------
// Mean-pool over l from bf16 Vb: PO[h*64+b] = mean_l Vb[l][h][b].
// ---------------------------------------------------------------------------
__global__ void pool_k(const u16* __restrict__ Vb, float* __restrict__ PO)
{
    __shared__ float red[4][64];
    int h = blockIdx.x;
    int b = threadIdx.x & 63;
    int lg = threadIdx.x >> 6;               // 0..3
    const u16* p = &Vb[(size_t)h * BB + b];
    float s = 0.f;
    for (int l = lg; l < LSEQ; l += 4) s += b2f16(p[(size_t)l * HD * BB]);
    red[lg][b] = s;
    __syncthreads();
    if (threadIdx.x < 64) {
        float t = red[0][b] + red[1][b] + red[2][b] + red[3][b];
        PO[h * BB + b] = t * (1.0f / LSEQ);
    }
}

// ---------------------------------------------------------------------------
// Decoder: out[b,c] = PO[:,b] . dec_w[:,c] + dec_b[c]
// ---------------------------------------------------------------------------
__global__ void dec_k(const float* __restrict__ PO, const float* __restrict__ w,
                      const float* __restrict__ bias, float* __restrict__ out)
{
    int t = blockIdx.x * 256 + threadIdx.x;
    if (t >= BB * 10) return;
    int cc = t % 10, b = t / 10;
    float acc = bias[cc];
    for (int hh = 0; hh < HD; hh++)
        acc = fmaf(PO[hh * BB + b], w[hh * 10 + cc], acc);
    out[t] = acc;
}

// ---------------------------------------------------------------------------
extern "C" void kernel_launch(void* const* d_in, const int* in_sizes, int n_in,
                              void* d_out, int out_size, void* d_ws, size_t ws_size,
                              hipStream_t stream)
{
    const float* x   = (const float*)d_in[0];
    const float* ew  = (const float*)d_in[1];
    const float* eb  = (const float*)d_in[2];
    const float* ldt = (const float*)d_in[3];
    const float* lar = (const float*)d_in[4];
    const float* aim = (const float*)d_in[5];
    const float* cre = (const float*)d_in[6];
    const float* cim = (const float*)d_in[7];
    const float* Dp  = (const float*)d_in[8];
    const float* lng = (const float*)d_in[9];
    const float* lnb = (const float*)d_in[10];
    const float* fng = (const float*)d_in[11];
    const float* fnb = (const float*)d_in[12];
    const float* dw  = (const float*)d_in[13];
    const float* db  = (const float*)d_in[14];
    float* out = (float*)d_out;

    const size_t SZ  = (size_t)BB * LSEQ * HD;       // 25,690,112 elems
    const size_t SZB = (size_t)BB * LPADROWS * HD;   // 26,214,400 u16 slots
    const size_t PP  = (size_t)NLAY * HD * NST;      // 196,608
    u16*   Vb  = (u16*)d_ws;                // bf16 residual stream [l][h][b]
    u16*   V2  = Vb + SZB;                  // bf16 pre-LN buffer (w/ slack)
    float* PAR = (float*)(V2 + SZB);
    float* lamr = PAR,        * lami = PAR + PP;
    float* dtr  = PAR + 2*PP, * dti  = PAR + 3*PP;
    float* c2r  = PAR + 4*PP, * c2i  = PAR + 5*PP;
    u16* KA = (u16*)(PAR + 6 * PP);                  // 6*512*848 u16
    float* PO = PAR + 6 * PP + (NLAY * HD * NKA) / 2;
    float* xT = PO + BB * HD;                        // 784*64 fp32
    // total ~117 MB

    precompute_k<<<(NLAY * HD * NST + 255) / 256, 256, 0, stream>>>(
        ldt, lar, aim, cre, cim, lamr, lami, dtr, dti, c2r, c2i);
    kq_k<<<(NLAY * HD * 49) / 256, 256, 0, stream>>>(
        lamr, lami, dtr, dti, c2r, c2i, KA);
    xt_k<<<(LSEQ * BB) / 256, 256, 0, stream>>>(x, xT);
    encoder_k<<<(LSEQ * HD * 8) / 256, 256, 0, stream>>>(xT, ew, eb, Vb);

    for (int i = 0; i < NLAY; i++) {
        conv_k<<<512 * NCH, 128, 0, stream>>>(
            Vb, V2, KA + (size_t)i * HD * NKA, Dp + i * HD);
        lnT_k<<<LSEQ, 512, 0, stream>>>(V2, Vb, lng + i * HD, lnb + i * HD);
    }
    lnT_k<<<LSEQ, 512, 0, stream>>>(Vb, Vb, fng, fnb);  // final LN in place
    pool_k<<<HD, 256, 0, stream>>>(Vb, PO);
    dec_k<<<(BB * 10 + 255) / 256, 256, 0, stream>>>(PO, dw, db, out);
}